// Round 34
// baseline (315.122 us; speedup 1.0000x reference)
//
#include <hip/hip_runtime.h>

// AffinityPropagate (CSPN): B=8, C=32, H=W=256, K=3, prop_time=16.
// R33: R32 + halo-once. Carried pipeline state is the 6-wide halo-expanded
// row (mkrb'd ONCE when the value is produced) instead of raw float4
// (re-mkrb'd at every consuming stage). Shfl (ds_bpermute) count per front:
// 24 -> 8, removing ~16 LDS-path ops from the serial stage chain.
// Arithmetic bit-identical (same mkrb results, same fmaf order).
// VGPR grows ~116->~150-190 — free: grid supplies only 2 WGs/CU.

#define B_ 8
#define C_ 32
#define H_ 256
#define W_ 256
#define CHUNK 32

// Row-contiguous weights: wts[((b*H + h)*9 + j)*W + w]
__global__ __launch_bounds__(256)
void prep_weights_kernel(const float* __restrict__ guided,
                         const float* __restrict__ depth,
                         float* __restrict__ wts,
                         int total /* B*H*W */) {
    int idx = blockIdx.x * 256 + threadIdx.x;
    if (idx >= total) return;
    int b  = idx >> 16;        // H*W = 65536
    int hw = idx & 0xFFFF;
    int h  = hw >> 8;
    int w  = hw & 255;
    const float* gp = guided + (((size_t)b * 8) << 16) + hw;
    float g[8];
    float m = -3.4e38f;
#pragma unroll
    for (int j = 0; j < 8; j++) { g[j] = gp[(size_t)j << 16]; m = fmaxf(m, g[j]); }
    float s = 0.f;
#pragma unroll
    for (int j = 0; j < 8; j++) { g[j] = expf(g[j] - m); s += g[j]; }
    float inv = 1.0f / s;
    float d = depth[(((size_t)b) << 16) + hw];
    bool fixed = d > 0.f;   // sign(depth) is 0/1 (depth >= 0)
    float* wp = wts + ((size_t)(b * H_ + h) * 9) * W_ + w;
#pragma unroll
    for (int j = 0; j < 9; j++) {
        float v;
        if (j == 4) v = fixed ? 1.f : 0.f;            // center
        else        v = fixed ? 0.f : g[j - (j > 4 ? 1 : 0)] * inv;
        wp[(size_t)j * W_] = v;
    }
}

__device__ __forceinline__ float4 zero4() { return make_float4(0.f, 0.f, 0.f, 0.f); }

__device__ __forceinline__ float4 ldxrow(const float* xc, int row, int w0) {
    if (row < 0 || row >= H_) return zero4();
    return *reinterpret_cast<const float4*>(xc + (size_t)row * W_ + w0);
}

// halo-expand a float4 row into 6-wide form (2 shfl) — done ONCE per value
__device__ __forceinline__ void mkrb6(float4 v, bool hasL, bool hasR, float r[6]) {
    float lh = __shfl_up(v.w, 1);
    float rh = __shfl_down(v.x, 1);
    r[0] = hasL ? lh : 0.f;
    r[1] = v.x; r[2] = v.y; r[3] = v.z; r[4] = v.w;
    r[5] = hasR ? rh : 0.f;
}

// acc[k] += wgt[3i+j][k] * ri[k+j]  — same fmaf order as R3..R32 (passed).
__device__ __forceinline__ void stencil4v(const float wgt[9][4],
                                          const float r0[6], const float r1[6],
                                          const float r2[6], float acc[4]) {
#pragma unroll
    for (int j = 0; j < 3; ++j)
#pragma unroll
        for (int k = 0; k < 4; ++k)
            acc[k] = fmaf(wgt[0 * 3 + j][k], r0[k + j], acc[k]);
#pragma unroll
    for (int j = 0; j < 3; ++j)
#pragma unroll
        for (int k = 0; k < 4; ++k)
            acc[k] = fmaf(wgt[1 * 3 + j][k], r1[k + j], acc[k]);
#pragma unroll
    for (int j = 0; j < 3; ++j)
#pragma unroll
        for (int k = 0; k < 4; ++k)
            acc[k] = fmaf(wgt[2 * 3 + j][k], r2[k + j], acc[k]);
}

// Row-contiguous: row r's 9 vectors live in one 9KB block.
__device__ __forceinline__ void load_wrow(const float* wb, int row, int w0,
                                          float (&w)[9][4]) {
    int qc = min(max(row, 0), H_ - 1);   // clamp; guarded consumers ignore
    const float* wp = wb + (size_t)qc * 9 * W_ + w0;
#pragma unroll
    for (int j = 0; j < 9; ++j) {
        float4 v = *reinterpret_cast<const float4*>(wp + j * W_);
        w[j][0] = v.x; w[j][1] = v.y; w[j][2] = v.z; w[j][3] = v.w;
    }
}

#define CP6(dst, src) _Pragma("unroll") for (int t6 = 0; t6 < 6; ++t6) dst[t6] = src[t6];

// 4 independent pipeline waves per 256-thread WG (ty = channel offset).
// All 4 waves share (b, hblk) -> same weight rows (L1 dedup).
__global__ __launch_bounds__(256)
void prop_wave_kernel(const float* __restrict__ xin,
                      const float* __restrict__ wts,
                      float* __restrict__ xout) {
    const int tx = threadIdx.x;            // 0..63
    const int ty = threadIdx.y;            // 0..3 (independent wave)
    const int h0 = blockIdx.x * CHUNK;
    const int c  = blockIdx.y * 4 + ty;    // 4 channels per block
    const int b  = blockIdx.z;
    const int w0 = tx * 4;
    const size_t plane = (size_t)H_ * W_;
    const bool hasL = (tx > 0), hasR = (tx < 63);
    const int f0 = h0 - 3;

    const float* xc = xin + ((size_t)b * C_ + c) * plane;
    const float* wb = wts + (size_t)b * H_ * 9 * W_;
    float*       oc = xout + ((size_t)b * C_ + c) * plane;

    // carried state: 6-wide halo-expanded rows
    float x6m[6], x6q[6], x6p[6];                    // x rows f-1, f, f+1
    float s1a6[6], s1b6[6], s2a6[6], s2b6[6], s3a6[6], s3b6[6];
    mkrb6(ldxrow(xc, f0 - 1, w0), hasL, hasR, x6m);
    mkrb6(ldxrow(xc, f0,     w0), hasL, hasR, x6q);
    mkrb6(ldxrow(xc, f0 + 1, w0), hasL, hasR, x6p);
#pragma unroll
    for (int t = 0; t < 6; ++t) {
        s1a6[t] = 0.f; s1b6[t] = 0.f;
        s2a6[t] = 0.f; s2b6[t] = 0.f;
        s3a6[t] = 0.f; s3b6[t] = 0.f;
    }
    // 4 rotating weight-row buffers: rows f, f-1, f-2, f-3
    float wg0[9][4], wg1[9][4], wg2[9][4], wg3[9][4];
    load_wrow(wb, f0,     w0, wg0);
    load_wrow(wb, f0 - 1, w0, wg1);
    load_wrow(wb, f0 - 2, w0, wg2);
    load_wrow(wb, f0 - 3, w0, wg3);

    auto front = [&](int f, const float (&w1)[9][4], const float (&w2)[9][4],
                     const float (&w3)[9][4], float (&w4)[9][4]) {
        // s1[f] -> halo-expand once
        float4 n1 = zero4();
        if (f >= 0 && f < H_) {
            float acc[4] = {0.f, 0.f, 0.f, 0.f};
            stencil4v(w1, x6m, x6q, x6p, acc);
            n1 = make_float4(acc[0], acc[1], acc[2], acc[3]);
        }
        float n1rb[6]; mkrb6(n1, hasL, hasR, n1rb);
        // s2[f-1]
        float4 n2 = zero4();
        if (f - 1 >= 0 && f - 1 < H_) {
            float acc[4] = {0.f, 0.f, 0.f, 0.f};
            stencil4v(w2, s1a6, s1b6, n1rb, acc);
            n2 = make_float4(acc[0], acc[1], acc[2], acc[3]);
        }
        float n2rb[6]; mkrb6(n2, hasL, hasR, n2rb);
        // s3[f-2]
        float4 n3 = zero4();
        if (f - 2 >= 0 && f - 2 < H_) {
            float acc[4] = {0.f, 0.f, 0.f, 0.f};
            stencil4v(w3, s2a6, s2b6, n2rb, acc);
            n3 = make_float4(acc[0], acc[1], acc[2], acc[3]);
        }
        float n3rb[6]; mkrb6(n3, hasL, hasR, n3rb);
        // s4[f-3] -> store (consumes w4, freeing it for the reload below)
        const int q = f - 3;
        if (q >= h0 && q < h0 + CHUNK) {
            float acc[4] = {0.f, 0.f, 0.f, 0.f};
            stencil4v(w4, s3a6, s3b6, n3rb, acc);
            *reinterpret_cast<float4*>(oc + (size_t)q * W_ + w0) =
                make_float4(acc[0], acc[1], acc[2], acc[3]);
        }
        // reload w4 with row f+1 (next front's s1 weights); prefetch x[f+2]
        load_wrow(wb, f + 1, w0, w4);
        float4 xn = ldxrow(xc, f + 2, w0);
        // rotate carried 6-wide windows (register moves; mkrb only for xn)
        CP6(x6m, x6q); CP6(x6q, x6p); mkrb6(xn, hasL, hasR, x6p);
        CP6(s1a6, s1b6); CP6(s1b6, n1rb);
        CP6(s2a6, s2b6); CP6(s2b6, n2rb);
        CP6(s3a6, s3b6); CP6(s3b6, n3rb);
    };

    // 36 unrolled fronts (9 rotations of the named weight buffers)...
    for (int u = 0; u < 36; u += 4) {
        front(f0 + u + 0, wg0, wg1, wg2, wg3);   // loads f0+u+1 -> wg3
        front(f0 + u + 1, wg3, wg0, wg1, wg2);   // loads f0+u+2 -> wg2
        front(f0 + u + 2, wg2, wg3, wg0, wg1);   // loads f0+u+3 -> wg1
        front(f0 + u + 3, wg1, wg2, wg3, wg0);   // loads f0+u+4 -> wg0
    }
    // ...+ 2 peeled fronts (36, 37). Fronts 38/39 are dead (R32).
    front(f0 + 36, wg0, wg1, wg2, wg3);
    front(f0 + 37, wg3, wg0, wg1, wg2);
}

extern "C" void kernel_launch(void* const* d_in, const int* in_sizes, int n_in,
                              void* d_out, int out_size, void* d_ws, size_t ws_size,
                              hipStream_t stream) {
    const float* x      = (const float*)d_in[0];
    const float* guided = (const float*)d_in[1];
    const float* depth  = (const float*)d_in[2];
    // d_in[3] = prop_time; fixed to 16 by setup_inputs.
    const int DISPATCHES = 4;    // 16 steps, 4 per dispatch

    float* xbuf = (float*)d_ws;                                   // 64 MB
    float* wts  = (float*)((char*)d_ws +
                           (size_t)B_ * C_ * H_ * W_ * sizeof(float)); // 18.9 MB
    float* out  = (float*)d_out;

    int total = B_ * H_ * W_;
    hipLaunchKernelGGL(prep_weights_kernel, dim3((total + 255) / 256), dim3(256),
                       0, stream, guided, depth, wts, total);

    // 8 hblk x 8 cgroup x 8 b = 512 WGs x 4 waves = 2048 wave-tasks
    dim3 grid(H_ / CHUNK, C_ / 4, B_), block(64, 4, 1);
    const float* src = x;
    for (int t = 0; t < DISPATCHES; ++t) {
        float* dst = (t == DISPATCHES - 1) ? out : ((t % 2 == 0) ? xbuf : out);
        hipLaunchKernelGGL(prop_wave_kernel, grid, block, 0, stream,
                           src, wts, dst);
        src = dst;
    }
}

// Round 35
// 190.385 us; speedup vs baseline: 1.6552x; 1.6552x over previous
//
#include <hip/hip_runtime.h>

// AffinityPropagate (CSPN): B=8, C=32, H=W=256, K=3, prop_time=16.
// R34 = R32 revert (final). R33's halo-once pushed VGPR 120->132 across the
// 128 tier -> occupancy halved -> 1.66x regression. R32 config: CHUNK=32
// wave-autonomous 4-step register pipeline (no LDS, no barriers), 4 channel-
// waves per WG sharing weight rows (L1 dedup), row-contiguous weights,
// dead fronts peeled (38 fronts). 189.5us timed, 3.46x vs R3 baseline.

#define B_ 8
#define C_ 32
#define H_ 256
#define W_ 256
#define CHUNK 32

// Row-contiguous weights: wts[((b*H + h)*9 + j)*W + w]
__global__ __launch_bounds__(256)
void prep_weights_kernel(const float* __restrict__ guided,
                         const float* __restrict__ depth,
                         float* __restrict__ wts,
                         int total /* B*H*W */) {
    int idx = blockIdx.x * 256 + threadIdx.x;
    if (idx >= total) return;
    int b  = idx >> 16;        // H*W = 65536
    int hw = idx & 0xFFFF;
    int h  = hw >> 8;
    int w  = hw & 255;
    const float* gp = guided + (((size_t)b * 8) << 16) + hw;
    float g[8];
    float m = -3.4e38f;
#pragma unroll
    for (int j = 0; j < 8; j++) { g[j] = gp[(size_t)j << 16]; m = fmaxf(m, g[j]); }
    float s = 0.f;
#pragma unroll
    for (int j = 0; j < 8; j++) { g[j] = expf(g[j] - m); s += g[j]; }
    float inv = 1.0f / s;
    float d = depth[(((size_t)b) << 16) + hw];
    bool fixed = d > 0.f;   // sign(depth) is 0/1 (depth >= 0)
    float* wp = wts + ((size_t)(b * H_ + h) * 9) * W_ + w;
#pragma unroll
    for (int j = 0; j < 9; j++) {
        float v;
        if (j == 4) v = fixed ? 1.f : 0.f;            // center
        else        v = fixed ? 0.f : g[j - (j > 4 ? 1 : 0)] * inv;
        wp[(size_t)j * W_] = v;
    }
}

__device__ __forceinline__ float4 zero4() { return make_float4(0.f, 0.f, 0.f, 0.f); }

__device__ __forceinline__ float4 ldxrow(const float* xc, int row, int w0) {
    if (row < 0 || row >= H_) return zero4();
    return *reinterpret_cast<const float4*>(xc + (size_t)row * W_ + w0);
}

// acc[k] += wgt[3i+j][k] * rb[i][k+j]  — same fmaf order as R3..R32 (passed).
__device__ __forceinline__ void stencil4(const float wgt[9][4],
                                         const float rb[3][6],
                                         float acc[4]) {
#pragma unroll
    for (int i = 0; i < 3; ++i)
#pragma unroll
        for (int j = 0; j < 3; ++j)
#pragma unroll
            for (int k = 0; k < 4; ++k)
                acc[k] = fmaf(wgt[i * 3 + j][k], rb[i][k + j], acc[k]);
}

__device__ __forceinline__ void mkrb(float4 v, bool hasL, bool hasR, float rbrow[6]) {
    float lh = __shfl_up(v.w, 1);
    float rh = __shfl_down(v.x, 1);
    rbrow[0] = hasL ? lh : 0.f;
    rbrow[1] = v.x; rbrow[2] = v.y; rbrow[3] = v.z; rbrow[4] = v.w;
    rbrow[5] = hasR ? rh : 0.f;
}

// Row-contiguous: row r's 9 vectors live in one 9KB block.
__device__ __forceinline__ void load_wrow(const float* wb, int row, int w0,
                                          float (&w)[9][4]) {
    int qc = min(max(row, 0), H_ - 1);   // clamp; guarded consumers ignore
    const float* wp = wb + (size_t)qc * 9 * W_ + w0;
#pragma unroll
    for (int j = 0; j < 9; ++j) {
        float4 v = *reinterpret_cast<const float4*>(wp + j * W_);
        w[j][0] = v.x; w[j][1] = v.y; w[j][2] = v.z; w[j][3] = v.w;
    }
}

// 4 independent pipeline waves per 256-thread WG (ty = channel offset).
// All 4 waves share (b, hblk) -> same weight rows (L1 dedup).
__global__ __launch_bounds__(256)
void prop_wave_kernel(const float* __restrict__ xin,
                      const float* __restrict__ wts,
                      float* __restrict__ xout) {
    const int tx = threadIdx.x;            // 0..63
    const int ty = threadIdx.y;            // 0..3 (independent wave)
    const int h0 = blockIdx.x * CHUNK;
    const int c  = blockIdx.y * 4 + ty;    // 4 channels per block
    const int b  = blockIdx.z;
    const int w0 = tx * 4;
    const size_t plane = (size_t)H_ * W_;
    const bool hasL = (tx > 0), hasR = (tx < 63);
    const int f0 = h0 - 3;

    const float* xc = xin + ((size_t)b * C_ + c) * plane;
    const float* wb = wts + (size_t)b * H_ * 9 * W_;
    float*       oc = xout + ((size_t)b * C_ + c) * plane;

    // x window: rows f-1, f, f+1
    float4 xm = ldxrow(xc, f0 - 1, w0);
    float4 xq = ldxrow(xc, f0,     w0);
    float4 xp = ldxrow(xc, f0 + 1, w0);
    // carried 2-row windows per stage (zero-init feeds only guarded rows)
    float4 s1a = zero4(), s1b = zero4();   // s1[f-2], s1[f-1]
    float4 s2a = zero4(), s2b = zero4();   // s2[f-3], s2[f-2]
    float4 s3a = zero4(), s3b = zero4();   // s3[f-4], s3[f-3]
    // 4 rotating weight-row buffers: rows f, f-1, f-2, f-3
    float wg0[9][4], wg1[9][4], wg2[9][4], wg3[9][4];
    load_wrow(wb, f0,     w0, wg0);
    load_wrow(wb, f0 - 1, w0, wg1);
    load_wrow(wb, f0 - 2, w0, wg2);
    load_wrow(wb, f0 - 3, w0, wg3);

    auto front = [&](int f, const float (&w1)[9][4], const float (&w2)[9][4],
                     const float (&w3)[9][4], float (&w4)[9][4]) {
        // s1[f]
        float4 n1 = zero4();
        if (f >= 0 && f < H_) {
            float rb[3][6];
            mkrb(xm, hasL, hasR, rb[0]);
            mkrb(xq, hasL, hasR, rb[1]);
            mkrb(xp, hasL, hasR, rb[2]);
            float acc[4] = {0.f, 0.f, 0.f, 0.f};
            stencil4(w1, rb, acc);
            n1 = make_float4(acc[0], acc[1], acc[2], acc[3]);
        }
        // s2[f-1]
        float4 n2 = zero4();
        if (f - 1 >= 0 && f - 1 < H_) {
            float rb[3][6];
            mkrb(s1a, hasL, hasR, rb[0]);
            mkrb(s1b, hasL, hasR, rb[1]);
            mkrb(n1,  hasL, hasR, rb[2]);
            float acc[4] = {0.f, 0.f, 0.f, 0.f};
            stencil4(w2, rb, acc);
            n2 = make_float4(acc[0], acc[1], acc[2], acc[3]);
        }
        // s3[f-2]
        float4 n3 = zero4();
        if (f - 2 >= 0 && f - 2 < H_) {
            float rb[3][6];
            mkrb(s2a, hasL, hasR, rb[0]);
            mkrb(s2b, hasL, hasR, rb[1]);
            mkrb(n2,  hasL, hasR, rb[2]);
            float acc[4] = {0.f, 0.f, 0.f, 0.f};
            stencil4(w3, rb, acc);
            n3 = make_float4(acc[0], acc[1], acc[2], acc[3]);
        }
        // s4[f-3] -> store (consumes w4, freeing it for the reload below)
        const int q = f - 3;
        if (q >= h0 && q < h0 + CHUNK) {
            float rb[3][6];
            mkrb(s3a, hasL, hasR, rb[0]);
            mkrb(s3b, hasL, hasR, rb[1]);
            mkrb(n3,  hasL, hasR, rb[2]);
            float acc[4] = {0.f, 0.f, 0.f, 0.f};
            stencil4(w4, rb, acc);
            *reinterpret_cast<float4*>(oc + (size_t)q * W_ + w0) =
                make_float4(acc[0], acc[1], acc[2], acc[3]);
        }
        // reload w4 with row f+1 (next front's s1 weights); prefetch x[f+2]
        load_wrow(wb, f + 1, w0, w4);
        float4 xn = ldxrow(xc, f + 2, w0);
        // rotate data windows
        xm = xq; xq = xp; xp = xn;
        s1a = s1b; s1b = n1;
        s2a = s2b; s2b = n2;
        s3a = s3b; s3b = n3;
    };

    // 36 unrolled fronts (9 rotations of the named weight buffers)...
    for (int u = 0; u < 36; u += 4) {
        front(f0 + u + 0, wg0, wg1, wg2, wg3);   // loads f0+u+1 -> wg3
        front(f0 + u + 1, wg3, wg0, wg1, wg2);   // loads f0+u+2 -> wg2
        front(f0 + u + 2, wg2, wg3, wg0, wg1);   // loads f0+u+3 -> wg1
        front(f0 + u + 3, wg1, wg2, wg3, wg0);   // loads f0+u+4 -> wg0
    }
    // ...+ 2 peeled fronts (36, 37). Fronts 38/39 were dead: their stores
    // target q = h0+35/36 (outside chunk guard), ring writes unconsumed.
    front(f0 + 36, wg0, wg1, wg2, wg3);
    front(f0 + 37, wg3, wg0, wg1, wg2);
}

extern "C" void kernel_launch(void* const* d_in, const int* in_sizes, int n_in,
                              void* d_out, int out_size, void* d_ws, size_t ws_size,
                              hipStream_t stream) {
    const float* x      = (const float*)d_in[0];
    const float* guided = (const float*)d_in[1];
    const float* depth  = (const float*)d_in[2];
    // d_in[3] = prop_time; fixed to 16 by setup_inputs.
    const int DISPATCHES = 4;    // 16 steps, 4 per dispatch

    float* xbuf = (float*)d_ws;                                   // 64 MB
    float* wts  = (float*)((char*)d_ws +
                           (size_t)B_ * C_ * H_ * W_ * sizeof(float)); // 18.9 MB
    float* out  = (float*)d_out;

    int total = B_ * H_ * W_;
    hipLaunchKernelGGL(prep_weights_kernel, dim3((total + 255) / 256), dim3(256),
                       0, stream, guided, depth, wts, total);

    // 8 hblk x 8 cgroup x 8 b = 512 WGs x 4 waves = 2048 wave-tasks
    dim3 grid(H_ / CHUNK, C_ / 4, B_), block(64, 4, 1);
    const float* src = x;
    for (int t = 0; t < DISPATCHES; ++t) {
        float* dst = (t == DISPATCHES - 1) ? out : ((t % 2 == 0) ? xbuf : out);
        hipLaunchKernelGGL(prop_wave_kernel, grid, block, 0, stream,
                           src, wts, dst);
        src = dst;
    }
}